// Round 12
// baseline (189.133 us; speedup 1.0000x reference)
//
#include <hip/hip_runtime.h>

#define N_NEURONS 1024
#define TABLE_SIZE 65536
#define BATCH 8192
#define RPB 4                        // table rows (neurons) per block
#define NBLK (N_NEURONS / RPB)       // 256 blocks, 1 per CU
#define TPB 1024                     // 16 waves per block
#define QSIZE 8192                   // floats per stage (32 KB)
#define NSTG (TABLE_SIZE / QSIZE)    // 8 stages per row
#define NS (RPB * NSTG)              // 32 stages per block (contiguous 1 MB)
#define SPT (BATCH / TPB)            // 8 samples per thread
#define TS ((size_t)TABLE_SIZE)

// Streaming formulation, now PIPELINED:
//   stage sq: [issue global loads of stage sq+1 to regs]  (fly under gather)
//             [gather stage sq from buf[sq&1]]            (LDS, branchless)
//             [ds_write regs -> buf[(sq+1)&1]]            (vmcnt-waits loads)
//             [one __syncthreads]                         (both hazards covered)
// Hazards: write buf[(sq+1)&1]@sq vs reads of same buf@sq-1 are separated by
// barrier(sq-1); reads@sq+1 separated by barrier(sq). Single barrier/stage.
// Block b's table slice is contiguous: rows [4b,4b+4) = 1 MB streamed
// sequentially, fully-coalesced float4 -- no 64-B line waste (the measured
// ~6 TB/s line-request ceiling of the gather formulation, R6-R10).
__global__ __launch_bounds__(TPB) void qw_stream_kernel(
    const int* __restrict__ data,
    const float* __restrict__ table,
    float* __restrict__ part)        // [NBLK][BATCH]
{
    __shared__ float buf[2][QSIZE];  // 64 KB static LDS

    const int b = blockIdx.x;
    const int t = threadIdx.x;

    // Preload this thread's 8 samples' indices for the block's 4 rows.
    int4 qidx[SPT];
#pragma unroll
    for (int k = 0; k < SPT; ++k) {
        qidx[k] = *reinterpret_cast<const int4*>(
            data + (size_t)(t * SPT + k) * N_NEURONS + b * RPB);
    }

    float acc[SPT];
#pragma unroll
    for (int k = 0; k < SPT; ++k) acc[k] = 0.0f;

    // Block's contiguous table slice: stage sq = floats [sq*QSIZE, +QSIZE).
    const float* __restrict__ tbase = table + (size_t)b * RPB * TS;

#define LOAD_STAGE(sq, A, B)                                               \
    {                                                                      \
        const float* __restrict__ s_ = tbase + (size_t)(sq) * QSIZE;       \
        A = *reinterpret_cast<const float4*>(s_ + t * 4);                  \
        B = *reinterpret_cast<const float4*>(s_ + TPB * 4 + t * 4);        \
    }
#define STORE_STAGE(dst, A, B)                                             \
    {                                                                      \
        *reinterpret_cast<float4*>(&buf[dst][t * 4]) = A;                  \
        *reinterpret_cast<float4*>(&buf[dst][TPB * 4 + t * 4]) = B;        \
    }

    float4 sa, sb;
    LOAD_STAGE(0, sa, sb);
    STORE_STAGE(0, sa, sb);
    __syncthreads();

#pragma unroll
    for (int sq = 0; sq < NS; ++sq) {
        const int cur = sq & 1;
        if (sq + 1 < NS) LOAD_STAGE(sq + 1, sa, sb);   // in flight under gather

        const int r  = sq >> 3;                        // row 0..3 (compile-time)
        const int lo = (sq & (NSTG - 1)) * QSIZE;
#pragma unroll
        for (int k = 0; k < SPT; ++k) {
            const int idx = (r == 0) ? qidx[k].x
                          : (r == 1) ? qidx[k].y
                          : (r == 2) ? qidx[k].z
                          :            qidx[k].w;
            const unsigned rel = (unsigned)(idx - lo);
            const float v = buf[cur][rel & (QSIZE - 1)];   // masked: never OOB
            acc[k] += (rel < (unsigned)QSIZE) ? v : 0.0f;  // cndmask
        }

        if (sq + 1 < NS) STORE_STAGE(cur ^ 1, sa, sb);     // waits vmcnt
        __syncthreads();                                   // single barrier/stage
    }
#undef LOAD_STAGE
#undef STORE_STAGE

    // per-block per-sample partials: 8 consecutive floats/thread, two float4
    float* __restrict__ dst = part + (size_t)b * BATCH + t * SPT;
    *reinterpret_cast<float4*>(dst)     = make_float4(acc[0], acc[1], acc[2], acc[3]);
    *reinterpret_cast<float4*>(dst + 4) = make_float4(acc[4], acc[5], acc[6], acc[7]);
}

// out[i] = sum_b part[b][i]   (8 MB streamed, coalesced)
__global__ __launch_bounds__(256) void qw_reduce_kernel(
    const float* __restrict__ part,
    float* __restrict__ out)
{
    const int i = blockIdx.x * 256 + threadIdx.x;
    float s0 = 0.0f, s1 = 0.0f, s2 = 0.0f, s3 = 0.0f;
#pragma unroll 4
    for (int b = 0; b < NBLK; b += 4) {
        s0 += part[(size_t)(b + 0) * BATCH + i];
        s1 += part[(size_t)(b + 1) * BATCH + i];
        s2 += part[(size_t)(b + 2) * BATCH + i];
        s3 += part[(size_t)(b + 3) * BATCH + i];
    }
    out[i] = (s0 + s1) + (s2 + s3);
}

// Mid fallback (ws >= 256 KB): R2-style neuron-major partials, ~92 us.
#define MF_NGROUPS 8
#define MF_NPG 128
#define MF_SPB 128
__global__ __launch_bounds__(256) void qw_partial_kernel(
    const int* __restrict__ data,
    const float* __restrict__ table,
    float* __restrict__ part)           // [MF_NGROUPS][BATCH]
{
    const int b      = blockIdx.x;
    const int g      = b & (MF_NGROUPS - 1);
    const int sub    = b >> 3;
    const int t      = threadIdx.x;
    const int h      = t >> 7;
    const int sid    = t & (MF_SPB - 1);
    const int sample = sub * MF_SPB + sid;
    const int jbase  = g * MF_NPG + h * 64;

    const int* __restrict__ drow = data + (size_t)sample * N_NEURONS + jbase;
    float acc = 0.0f;
#pragma unroll
    for (int jo = 0; jo < 64; jo += 16) {
        const int4 i0 = *reinterpret_cast<const int4*>(drow + jo);
        const int4 i1 = *reinterpret_cast<const int4*>(drow + jo + 4);
        const int4 i2 = *reinterpret_cast<const int4*>(drow + jo + 8);
        const int4 i3 = *reinterpret_cast<const int4*>(drow + jo + 12);
        const float* __restrict__ tp = table + (size_t)(jbase + jo) * TS;
        acc += tp[(size_t) 0 * TS + i0.x] + tp[(size_t) 1 * TS + i0.y]
             + tp[(size_t) 2 * TS + i0.z] + tp[(size_t) 3 * TS + i0.w]
             + tp[(size_t) 4 * TS + i1.x] + tp[(size_t) 5 * TS + i1.y]
             + tp[(size_t) 6 * TS + i1.z] + tp[(size_t) 7 * TS + i1.w]
             + tp[(size_t) 8 * TS + i2.x] + tp[(size_t) 9 * TS + i2.y]
             + tp[(size_t)10 * TS + i2.z] + tp[(size_t)11 * TS + i2.w]
             + tp[(size_t)12 * TS + i3.x] + tp[(size_t)13 * TS + i3.y]
             + tp[(size_t)14 * TS + i3.z] + tp[(size_t)15 * TS + i3.w];
    }
    __shared__ float lsum[MF_SPB];
    if (h == 0) lsum[sid] = acc;
    __syncthreads();
    if (h == 1) part[(size_t)g * BATCH + sample] = lsum[sid] + acc;
}

__global__ __launch_bounds__(256) void qw_reduce8_kernel(
    const float* __restrict__ part,
    float* __restrict__ out)
{
    const int i = blockIdx.x * 256 + threadIdx.x;
    float s = 0.0f;
#pragma unroll
    for (int g = 0; g < MF_NGROUPS; ++g) s += part[(size_t)g * BATCH + i];
    out[i] = s;
}

// Last-resort fallback (no workspace).
__global__ __launch_bounds__(256) void qw_gather_kernel(
    const int* __restrict__ data,
    const float* __restrict__ table,
    float* __restrict__ out)
{
    const int gtid   = blockIdx.x * blockDim.x + threadIdx.x;
    const int sample = gtid >> 6;
    const int lane   = threadIdx.x & 63;
    if (sample >= BATCH) return;
    const int* __restrict__ row = data + (size_t)sample * N_NEURONS;
    float acc = 0.0f;
#pragma unroll
    for (int k = 0; k < 4; ++k) {
        const int jb = 256 * k + 4 * lane;
        const int4 idx4 = *reinterpret_cast<const int4*>(row + jb);
        acc += table[(size_t)(jb + 0) * TS + idx4.x];
        acc += table[(size_t)(jb + 1) * TS + idx4.y];
        acc += table[(size_t)(jb + 2) * TS + idx4.z];
        acc += table[(size_t)(jb + 3) * TS + idx4.w];
    }
#pragma unroll
    for (int off = 32; off >= 1; off >>= 1) acc += __shfl_xor(acc, off, 64);
    if (lane == 0) out[sample] = acc;
}

extern "C" void kernel_launch(void* const* d_in, const int* in_sizes, int n_in,
                              void* d_out, int out_size, void* d_ws, size_t ws_size,
                              hipStream_t stream)
{
    const int*   data  = (const int*)d_in[0];    // [BATCH, N_NEURONS] int32
    const float* table = (const float*)d_in[1];  // [N_NEURONS, TABLE_SIZE] float32
    float*       out   = (float*)d_out;          // [BATCH] float32

    const size_t stream_bytes = (size_t)NBLK * BATCH * sizeof(float);       // 8 MB
    const size_t mid_bytes    = (size_t)MF_NGROUPS * BATCH * sizeof(float); // 256 KB

    if (ws_size >= stream_bytes) {
        float* part = (float*)d_ws;
        qw_stream_kernel<<<NBLK, TPB, 0, stream>>>(data, table, part);
        qw_reduce_kernel<<<BATCH / 256, 256, 0, stream>>>(part, out);
    } else if (ws_size >= mid_bytes) {
        float* part = (float*)d_ws;
        qw_partial_kernel<<<(BATCH / MF_SPB) * MF_NGROUPS, 256, 0, stream>>>(
            data, table, part);
        qw_reduce8_kernel<<<BATCH / 256, 256, 0, stream>>>(part, out);
    } else {
        qw_gather_kernel<<<BATCH / 4, 256, 0, stream>>>(data, table, out);
    }
}

// Round 13
// 84.235 us; speedup vs baseline: 2.2453x; 2.2453x over previous
//
#include <hip/hip_runtime.h>

#define N_NEURONS 1024
#define TABLE_SIZE 65536
#define BATCH 8192
#define NGROUPS 8            // one neuron-group per XCD (block b -> XCD b%8)
#define NPG 128              // neurons (table rows) per group
#define SPB 128              // samples per block
#define NCHUNK 8             // 8 chunks x 16-row window = 128 rows
#define TS ((size_t)TABLE_SIZE)

// Measured-best chassis (R6, 84.2 us = 530 MB line traffic / 6.3 TB/s):
// neuron-major partials, XCD-affine groups, register double-buffered gathers
// with raw s_barrier pacing (no vmcnt drain). Session R3-R12 established that
// cache-locality pacing, kernel-boundary phasing, and LDS streaming all land
// ABOVE this kernel: the device moves random 64-B lines at ~6.3 TB/s
// regardless of source (HBM/L2/LLC), so 8.4M gathers x 64 B = 537 MB / 6.3
// TB/s ~ 84 us is the structural floor for this access pattern.
__global__ __launch_bounds__(256) void qw_partial_kernel(
    const int* __restrict__ data,
    const float* __restrict__ table,
    float* __restrict__ part)           // [NGROUPS][BATCH]
{
    const int b      = blockIdx.x;
    const int g      = b & (NGROUPS - 1);
    const int sub    = b >> 3;
    const int t      = threadIdx.x;
    const int h      = t & 1;
    const int sid    = t >> 1;                       // 0..127
    const int sample = sub * SPB + sid;

    const int* __restrict__ dptr =
        data + (size_t)sample * N_NEURONS + g * NPG + h * 8;
    const float* __restrict__ tb =
        table + (size_t)(g * NPG + h * 8) * TABLE_SIZE;

#define IDX(c)  (*reinterpret_cast<const int4*>(dptr + (c) * 16))
#define IDX2(c) (*reinterpret_cast<const int4*>(dptr + (c) * 16 + 4))

#define GATHER(d0,d1,d2,d3,d4,d5,d6,d7, c, I0, I1)                    \
    d0 = tb[((size_t)(c) * 16 + 0) * TS + (size_t)(I0).x];            \
    d1 = tb[((size_t)(c) * 16 + 1) * TS + (size_t)(I0).y];            \
    d2 = tb[((size_t)(c) * 16 + 2) * TS + (size_t)(I0).z];            \
    d3 = tb[((size_t)(c) * 16 + 3) * TS + (size_t)(I0).w];            \
    d4 = tb[((size_t)(c) * 16 + 4) * TS + (size_t)(I1).x];            \
    d5 = tb[((size_t)(c) * 16 + 5) * TS + (size_t)(I1).y];            \
    d6 = tb[((size_t)(c) * 16 + 6) * TS + (size_t)(I1).z];            \
    d7 = tb[((size_t)(c) * 16 + 7) * TS + (size_t)(I1).w];

#define SUM8(d0,d1,d2,d3,d4,d5,d6,d7) \
    (((d0 + d1) + (d2 + d3)) + ((d4 + d5) + (d6 + d7)))

    // idx regs: p = even chunks' feed, q = odd chunks' feed (2 ahead)
    int4 p0 = IDX(0), p1 = IDX2(0);
    int4 q0 = IDX(1), q1 = IDX2(1);

    float A0,A1,A2,A3,A4,A5,A6,A7;
    float B0,B1,B2,B3,B4,B5,B6,B7;
    float acc = 0.0f;

    // prologue: chunk 0 gathers in flight
    GATHER(A0,A1,A2,A3,A4,A5,A6,A7, 0, p0, p1);

    // epoch 0: issue chunk1, prefetch idx2, pace, consume chunk0
    GATHER(B0,B1,B2,B3,B4,B5,B6,B7, 1, q0, q1);
    p0 = IDX(2); p1 = IDX2(2);
    __builtin_amdgcn_s_barrier();
    acc += SUM8(A0,A1,A2,A3,A4,A5,A6,A7);

    // epoch 1: issue chunk2, prefetch idx3, pace, consume chunk1
    GATHER(A0,A1,A2,A3,A4,A5,A6,A7, 2, p0, p1);
    q0 = IDX(3); q1 = IDX2(3);
    __builtin_amdgcn_s_barrier();
    acc += SUM8(B0,B1,B2,B3,B4,B5,B6,B7);

    // epoch 2: issue chunk3, prefetch idx4, pace, consume chunk2
    GATHER(B0,B1,B2,B3,B4,B5,B6,B7, 3, q0, q1);
    p0 = IDX(4); p1 = IDX2(4);
    __builtin_amdgcn_s_barrier();
    acc += SUM8(A0,A1,A2,A3,A4,A5,A6,A7);

    // epoch 3: issue chunk4, prefetch idx5, pace, consume chunk3
    GATHER(A0,A1,A2,A3,A4,A5,A6,A7, 4, p0, p1);
    q0 = IDX(5); q1 = IDX2(5);
    __builtin_amdgcn_s_barrier();
    acc += SUM8(B0,B1,B2,B3,B4,B5,B6,B7);

    // epoch 4: issue chunk5, prefetch idx6, pace, consume chunk4
    GATHER(B0,B1,B2,B3,B4,B5,B6,B7, 5, q0, q1);
    p0 = IDX(6); p1 = IDX2(6);
    __builtin_amdgcn_s_barrier();
    acc += SUM8(A0,A1,A2,A3,A4,A5,A6,A7);

    // epoch 5: issue chunk6, prefetch idx7, pace, consume chunk5
    GATHER(A0,A1,A2,A3,A4,A5,A6,A7, 6, p0, p1);
    q0 = IDX(7); q1 = IDX2(7);
    __builtin_amdgcn_s_barrier();
    acc += SUM8(B0,B1,B2,B3,B4,B5,B6,B7);

    // epoch 6: issue chunk7, pace, consume chunk6
    GATHER(B0,B1,B2,B3,B4,B5,B6,B7, 7, q0, q1);
    __builtin_amdgcn_s_barrier();
    acc += SUM8(A0,A1,A2,A3,A4,A5,A6,A7);

    // epoch 7: consume chunk7
    acc += SUM8(B0,B1,B2,B3,B4,B5,B6,B7);

#undef GATHER
#undef SUM8
#undef IDX
#undef IDX2

    // combine the two halves of each sample (adjacent lanes)
    acc += __shfl_xor(acc, 1, 64);
    if (h == 0) {
        part[(size_t)g * BATCH + sample] = acc;
    }
}

// Pass 2: out[i] = sum_g part[g][i]
__global__ __launch_bounds__(256) void qw_reduce_kernel(
    const float* __restrict__ part,
    float* __restrict__ out)
{
    const int i = blockIdx.x * 256 + threadIdx.x;
    float s = 0.0f;
#pragma unroll
    for (int g = 0; g < NGROUPS; ++g) {
        s += part[(size_t)g * BATCH + i];
    }
    out[i] = s;
}

// Fallback in case d_ws is too small for partials.
__global__ __launch_bounds__(256) void qw_gather_kernel(
    const int* __restrict__ data,
    const float* __restrict__ table,
    float* __restrict__ out)
{
    const int gtid   = blockIdx.x * blockDim.x + threadIdx.x;
    const int sample = gtid >> 6;
    const int lane   = threadIdx.x & 63;
    if (sample >= BATCH) return;
    const int* __restrict__ row = data + (size_t)sample * N_NEURONS;
    float acc = 0.0f;
#pragma unroll
    for (int k = 0; k < 4; ++k) {
        const int jb = 256 * k + 4 * lane;
        const int4 idx4 = *reinterpret_cast<const int4*>(row + jb);
        acc += table[(size_t)(jb + 0) * TS + idx4.x];
        acc += table[(size_t)(jb + 1) * TS + idx4.y];
        acc += table[(size_t)(jb + 2) * TS + idx4.z];
        acc += table[(size_t)(jb + 3) * TS + idx4.w];
    }
#pragma unroll
    for (int off = 32; off >= 1; off >>= 1) acc += __shfl_xor(acc, off, 64);
    if (lane == 0) out[sample] = acc;
}

extern "C" void kernel_launch(void* const* d_in, const int* in_sizes, int n_in,
                              void* d_out, int out_size, void* d_ws, size_t ws_size,
                              hipStream_t stream)
{
    const int*   data  = (const int*)d_in[0];    // [BATCH, N_NEURONS] int32
    const float* table = (const float*)d_in[1];  // [N_NEURONS, TABLE_SIZE] float32
    float*       out   = (float*)d_out;          // [BATCH] float32

    const size_t need = (size_t)NGROUPS * BATCH * sizeof(float);  // 256 KB
    if (ws_size >= need) {
        float* part = (float*)d_ws;
        const int blocks = (BATCH / SPB) * NGROUPS;  // 512 = 2 blocks/CU
        qw_partial_kernel<<<blocks, 256, 0, stream>>>(data, table, part);
        qw_reduce_kernel<<<BATCH / 256, 256, 0, stream>>>(part, out);
    } else {
        qw_gather_kernel<<<BATCH / 4, 256, 0, stream>>>(data, table, out);
    }
}